// Round 5
// baseline (468.964 us; speedup 1.0000x reference)
//
#include <hip/hip_runtime.h>

#define KC 4096
#define DD 256
#define BB 32768
#define P_BETA 0.25f
#define P_DECAY 0.99f
#define P_EPS 1e-5f
#define TAU 0.5f

typedef __attribute__((ext_vector_type(8))) short bf16x8;
typedef __attribute__((ext_vector_type(4))) float f32x4;

static __device__ __forceinline__ unsigned short f2bf(float f) {
    unsigned int u = __float_as_uint(f);
    unsigned int r = (u + 0x7fffu + ((u >> 16) & 1u)) >> 16;
    return (unsigned short)r;
}
static __device__ __forceinline__ void gload_lds16(const void* g, void* s) {
    __builtin_amdgcn_global_load_lds(
        (const __attribute__((address_space(1))) unsigned int*)g,
        (__attribute__((address_space(3))) unsigned int*)s, 16, 0, 0);
}

// ---------------------------------------------------------------------------
// convert z -> bf16
// ---------------------------------------------------------------------------
__global__ __launch_bounds__(256) void convert_z_kernel(const float* __restrict__ src,
                                                        unsigned short* __restrict__ dst) {
    int t = blockIdx.x * 256 + threadIdx.x;
    float4 v = ((const float4*)src)[t];
    *(ushort4*)&dst[(size_t)t * 4] =
        make_ushort4(f2bf(v.x), f2bf(v.y), f2bf(v.z), f2bf(v.w));
}

// ---------------------------------------------------------------------------
// convert cb -> bf16, fused exact-f32 c_norm
// ---------------------------------------------------------------------------
__global__ __launch_bounds__(256) void convert_cb_kernel(const float* __restrict__ cb,
                                                         unsigned short* __restrict__ dst,
                                                         float* __restrict__ cn) {
    int t = blockIdx.x * 256 + threadIdx.x;
    int lane = threadIdx.x & 63;
    int row = blockIdx.x * 4 + (threadIdx.x >> 6);
    float4 v = ((const float4*)cb)[t];
    *(ushort4*)&dst[(size_t)t * 4] =
        make_ushort4(f2bf(v.x), f2bf(v.y), f2bf(v.z), f2bf(v.w));
    float s = v.x * v.x + v.y * v.y + v.z * v.z + v.w * v.w;
#pragma unroll
    for (int m = 32; m; m >>= 1) s += __shfl_xor(s, m);
    if (lane == 0) cn[row] = s;
}

// ---------------------------------------------------------------------------
// MFMA argmin screening (plain bf16), persistent A-tile, XOR swizzle.
// Emits per-row top-2 per K-half.
// ---------------------------------------------------------------------------
__global__ __launch_bounds__(256, 2) void
mfma_argmin_kernel(const unsigned short* __restrict__ zb,
                   const unsigned short* __restrict__ cbb,
                   const float* __restrict__ cn,
                   float4* __restrict__ cand) {
    __shared__ unsigned short As[128 * 256];  // 64 KB persistent z-tile
    __shared__ unsigned short Bs[128 * 64];   // 16 KB per-step cb-tile

    const int tid = threadIdx.x;
    const int l = tid & 63, w = tid >> 6;
    const int xcd = blockIdx.x & 7;
    const int half = xcd >> 2;
    const int rb = (blockIdx.x >> 3) * 4 + (xcd & 3);
    const int row0 = rb * 128;
    const int col0 = half * 2048;
    const int wm = w & 1, wn = w >> 1;
    const int m_off = wm * 64, n_off = wn * 64;
    const int lm = l & 15, lq = l >> 4;

    {
        const int lrow = w * 2 + (l >> 5);
        const int coff = ((l & 31) ^ lrow) * 8;
#pragma unroll
        for (int i = 0; i < 16; ++i) {
            gload_lds16(zb + (size_t)(row0 + i * 8 + lrow) * DD + coff,
                        &As[(i * 8 + w * 2) * 256]);
        }
    }

    const int srow = l >> 3;
    const int scol = ((l & 7) ^ srow) * 8;
    const int g0 = w * 4;

    float best[16];
    int bidx[16];
#pragma unroll
    for (int s = 0; s < 16; ++s) { best[s] = 3.4e38f; bidx[s] = 0; }

    for (int kc = 0; kc < 2048; kc += 128) {
        f32x4 acc[4][4];
#pragma unroll
        for (int a = 0; a < 4; ++a)
#pragma unroll
            for (int b = 0; b < 4; ++b) acc[a][b] = (f32x4){0.f, 0.f, 0.f, 0.f};

        for (int dc = 0; dc < 4; ++dc) {
#pragma unroll
            for (int j = 0; j < 4; ++j) {
                const int g = g0 + j;
                const int br = col0 + kc + g * 8 + srow;
                gload_lds16(cbb + (size_t)br * DD + dc * 64 + scol, &Bs[g * 512]);
            }
            __syncthreads();
#pragma unroll
            for (int ks = 0; ks < 2; ++ks) {
                bf16x8 af[4], bfr[4];
                const int cbi = dc * 8 + ks * 4 + lq;
#pragma unroll
                for (int tm = 0; tm < 4; ++tm) {
                    int r = m_off + tm * 16 + lm;
                    af[tm] = *(const bf16x8*)&As[r * 256 + ((cbi ^ (r & 7)) * 8)];
                }
#pragma unroll
                for (int tn = 0; tn < 4; ++tn) {
                    int r = n_off + tn * 16 + lm;
                    bfr[tn] = *(const bf16x8*)&Bs[r * 64 + (((ks * 4 + lq) ^ (r & 7)) * 8)];
                }
#pragma unroll
                for (int tm = 0; tm < 4; ++tm)
#pragma unroll
                    for (int tn = 0; tn < 4; ++tn)
                        acc[tm][tn] = __builtin_amdgcn_mfma_f32_16x16x32_bf16(
                            af[tm], bfr[tn], acc[tm][tn], 0, 0, 0);
            }
            __syncthreads();
        }
#pragma unroll
        for (int tn = 0; tn < 4; ++tn) {
            const int col = col0 + kc + n_off + tn * 16 + lm;
            const float cnv = cn[col];
#pragma unroll
            for (int tm = 0; tm < 4; ++tm)
#pragma unroll
                for (int r = 0; r < 4; ++r) {
                    float dist = fmaf(-2.0f, acc[tm][tn][r], cnv);
                    int s = tm * 4 + r;
                    if (dist < best[s]) { best[s] = dist; bidx[s] = col; }
                }
        }
    }

    float v2[16];
    int i2[16];
#pragma unroll
    for (int s = 0; s < 16; ++s) { v2[s] = 3.4e38f; i2[s] = 0x7fffffff; }
#pragma unroll
    for (int m = 1; m < 16; m <<= 1) {
#pragma unroll
        for (int s = 0; s < 16; ++s) {
            float w1 = __shfl_xor(best[s], m); int j1 = __shfl_xor(bidx[s], m);
            float w2 = __shfl_xor(v2[s], m);   int j2 = __shfl_xor(i2[s], m);
            bool b = (w1 < best[s]) || (w1 == best[s] && j1 < bidx[s]);
            if (b) {
                bool c = (best[s] < w2) || (best[s] == w2 && bidx[s] < j2);
                v2[s] = c ? best[s] : w2; i2[s] = c ? bidx[s] : j2;
                best[s] = w1; bidx[s] = j1;
            } else {
                bool c = (w1 < v2[s]) || (w1 == v2[s] && j1 < i2[s]);
                v2[s] = c ? w1 : v2[s]; i2[s] = c ? j1 : i2[s];
            }
        }
    }

    float4* red = (float4*)As;
    if (lm == 0) {
#pragma unroll
        for (int tm = 0; tm < 4; ++tm)
#pragma unroll
            for (int r = 0; r < 4; ++r) {
                int s = tm * 4 + r;
                int row_local = m_off + tm * 16 + lq * 4 + r;
                red[wn * 128 + row_local] =
                    make_float4(best[s], __int_as_float(bidx[s]), v2[s], __int_as_float(i2[s]));
            }
    }
    __syncthreads();
    if (tid < 128) {
        float4 a = red[tid], b = red[128 + tid];
        float av1 = a.x, av2 = a.z; int ai1 = __float_as_int(a.y), ai2 = __float_as_int(a.w);
        float bv1 = b.x, bv2 = b.z; int bi1 = __float_as_int(b.y), bi2 = __float_as_int(b.w);
        float v1o, v2o; int i1o, i2o;
        bool bb = (bv1 < av1) || (bv1 == av1 && bi1 < ai1);
        if (bb) {
            v1o = bv1; i1o = bi1;
            bool c = (av1 < bv2) || (av1 == bv2 && ai1 < bi2);
            v2o = c ? av1 : bv2; i2o = c ? ai1 : bi2;
        } else {
            v1o = av1; i1o = ai1;
            bool c = (bv1 < av2) || (bv1 == av2 && bi1 < ai2);
            v2o = c ? bv1 : av2; i2o = c ? bi1 : ai2;
        }
        cand[(size_t)half * BB + row0 + tid] =
            make_float4(v1o, __int_as_float(i1o), v2o, __int_as_float(i2o));
    }
}

// ---------------------------------------------------------------------------
// merge halves; write provisional idx; append close calls to worklist
// ---------------------------------------------------------------------------
__global__ __launch_bounds__(256) void merge_kernel(
    const float4* __restrict__ cand, int* __restrict__ idx_i,
    float* __restrict__ idx_f, int4* __restrict__ wl, int* __restrict__ wl_cnt) {
    int i = blockIdx.x * 256 + threadIdx.x;
    float4 a = cand[i], b = cand[(size_t)BB + i];
    float av1 = a.x, av2 = a.z; int ai1 = __float_as_int(a.y), ai2 = __float_as_int(a.w);
    float bv1 = b.x, bv2 = b.z; int bi1 = __float_as_int(b.y), bi2 = __float_as_int(b.w);
    float v1o, v2o; int i1o, i2o;
    bool bb = (bv1 < av1) || (bv1 == av1 && bi1 < ai1);
    if (bb) {
        v1o = bv1; i1o = bi1;
        bool c = (av1 < bv2) || (av1 == bv2 && ai1 < bi2);
        v2o = c ? av1 : bv2; i2o = c ? ai1 : bi2;
    } else {
        v1o = av1; i1o = ai1;
        bool c = (bv1 < av2) || (bv1 == av2 && bi1 < ai2);
        v2o = c ? bv1 : av2; i2o = c ? bi1 : ai2;
    }
    idx_i[i] = i1o;
    idx_f[i] = (float)i1o;
    if (v2o - v1o < TAU) {
        int pos = atomicAdd(wl_cnt, 1);
        wl[pos] = make_int4(i, i1o, i2o, 0);
    }
}

// ---------------------------------------------------------------------------
// refine worklist rows exactly: one WAVE per row, coalesced float4 + shuffle
// ---------------------------------------------------------------------------
__global__ __launch_bounds__(256) void refine_kernel(
    const int4* __restrict__ wl, const int* __restrict__ wl_cnt,
    const float* __restrict__ z, const float* __restrict__ cb,
    const float* __restrict__ cn, int* __restrict__ idx_i,
    float* __restrict__ idx_f) {
    const int wave = (blockIdx.x * 256 + threadIdx.x) >> 6;  // 0..1023
    const int l = threadIdx.x & 63;
    const int n = *wl_cnt;
    for (int it = wave; it < n; it += 1024) {
        int4 e = wl[it];
        int i = e.x, k1 = e.y, k2 = e.z;
        float4 zv = ((const float4*)(z + (size_t)i * DD))[l];
        float4 p = ((const float4*)(cb + (size_t)k1 * DD))[l];
        float4 q = ((const float4*)(cb + (size_t)k2 * DD))[l];
        float s1 = zv.x * p.x + zv.y * p.y + zv.z * p.z + zv.w * p.w;
        float s2 = zv.x * q.x + zv.y * q.y + zv.z * q.z + zv.w * q.w;
#pragma unroll
        for (int m = 32; m; m >>= 1) { s1 += __shfl_xor(s1, m); s2 += __shfl_xor(s2, m); }
        float d1 = cn[k1] - 2.f * s1;
        float d2 = cn[k2] - 2.f * s2;
        int kb = (d2 < d1 || (d2 == d1 && k2 < k1)) ? k2 : k1;
        if (l == 0) { idx_i[i] = kb; idx_f[i] = (float)kb; }
    }
}

// ---------------------------------------------------------------------------
// histogram of final idx (int counts)
// ---------------------------------------------------------------------------
__global__ __launch_bounds__(256) void hist_kernel(const int* __restrict__ idx_i,
                                                   int* __restrict__ cnt) {
    int i = blockIdx.x * 256 + threadIdx.x;
    atomicAdd(&cnt[idx_i[i]], 1);
}

// ---------------------------------------------------------------------------
// exclusive prefix over 4096 bins (1 block); writes bin_start[KC]=B, cursors
// ---------------------------------------------------------------------------
__global__ __launch_bounds__(256) void prefix_kernel(const int* __restrict__ cnt,
                                                     int* __restrict__ bin_start,
                                                     int* __restrict__ cursor) {
    __shared__ int ls[257];
    const int t = threadIdx.x;
    int local[16];
    int s = 0;
#pragma unroll
    for (int j = 0; j < 16; ++j) { local[j] = s; s += cnt[t * 16 + j]; }
    ls[t + 1] = s;
    __syncthreads();
    if (t == 0) {
        ls[0] = 0;
        for (int j = 1; j <= 256; ++j) ls[j] += ls[j - 1];
    }
    __syncthreads();
    int off = ls[t];
#pragma unroll
    for (int j = 0; j < 16; ++j) {
        int v = off + local[j];
        bin_start[t * 16 + j] = v;
        cursor[t * 16 + j] = v;
    }
    if (t == 255) bin_start[KC] = ls[256];
}

// ---------------------------------------------------------------------------
// scatter row ids into buckets
// ---------------------------------------------------------------------------
__global__ __launch_bounds__(256) void scatter_ids_kernel(const int* __restrict__ idx_i,
                                                          int* __restrict__ cursor,
                                                          int* __restrict__ row_of) {
    int i = blockIdx.x * 256 + threadIdx.x;
    int pos = atomicAdd(&cursor[idx_i[i]], 1);
    row_of[pos] = i;
}

// ---------------------------------------------------------------------------
// z_q gather + commit partials (no atomics): 4 rows per block
// ---------------------------------------------------------------------------
__global__ __launch_bounds__(256) void zq_commit_kernel(const float* __restrict__ z,
                                                        const float* __restrict__ cb,
                                                        const int* __restrict__ idx_i,
                                                        float* __restrict__ zq,
                                                        float* __restrict__ commit_parts) {
    const int w = threadIdx.x >> 6, l = threadIdx.x & 63;
    const int i = blockIdx.x * 4 + w;
    const int k = idx_i[i];
    float4 zv = ((const float4*)z)[(size_t)i * 64 + l];
    float4 cv = ((const float4*)cb)[(size_t)k * 64 + l];
    ((float4*)zq)[(size_t)i * 64 + l] = cv;
    float dx = zv.x - cv.x, dy = zv.y - cv.y, dz = zv.z - cv.z, dq = zv.w - cv.w;
    float s = dx * dx + dy * dy + dz * dz + dq * dq;
#pragma unroll
    for (int m = 32; m; m >>= 1) s += __shfl_xor(s, m);
    __shared__ float ls[4];
    if (l == 0) ls[w] = s;
    __syncthreads();
    if (threadIdx.x == 0) commit_parts[blockIdx.x] = ls[0] + ls[1] + ls[2] + ls[3];
}

// ---------------------------------------------------------------------------
// single block: commit reduce + new_cluster + n
// ---------------------------------------------------------------------------
__global__ __launch_bounds__(256) void cluster_commit_kernel(
    const float* __restrict__ ema_cs, const int* __restrict__ cnt,
    const float* __restrict__ commit_parts, float* __restrict__ out_cluster,
    float* __restrict__ n_ws, float* __restrict__ out_commit) {
    const int t = threadIdx.x;
    float cs = 0.f;
    for (int j = t; j < BB / 4; j += 256) cs += commit_parts[j];
    float ns = 0.f;
    for (int j = t; j < KC; j += 256) {
        float nc = ema_cs[j] * P_DECAY + (float)cnt[j] * (1.0f - P_DECAY);
        out_cluster[j] = nc;
        ns += nc;
    }
#pragma unroll
    for (int m = 32; m; m >>= 1) { cs += __shfl_xor(cs, m); ns += __shfl_xor(ns, m); }
    __shared__ float lc[4], ln[4];
    if ((t & 63) == 0) { lc[t >> 6] = cs; ln[t >> 6] = ns; }
    __syncthreads();
    if (t == 0) {
        *out_commit = P_BETA * (lc[0] + lc[1] + lc[2] + lc[3]) / (float)((size_t)BB * DD);
        *n_ws = ln[0] + ln[1] + ln[2] + ln[3];
    }
}

// ---------------------------------------------------------------------------
// bucket sum of z rows per code + finalize ema_weight & codebook directly.
// One block per code; thread t owns dim t (coalesced 1 KB row reads).
// ---------------------------------------------------------------------------
__global__ __launch_bounds__(256) void bucketsum_finalize_kernel(
    const float* __restrict__ z, const int* __restrict__ row_of,
    const int* __restrict__ bin_start, const float* __restrict__ ema_w,
    const float* __restrict__ out_cluster, const float* __restrict__ n_ws,
    float* __restrict__ out_ema_w, float* __restrict__ out_codebook) {
    const int k = blockIdx.x;
    const int t = threadIdx.x;
    const int s = bin_start[k], e = bin_start[k + 1];
    float acc = 0.f;
    for (int j = s; j < e; ++j) {
        int r = row_of[j];
        acc += z[(size_t)r * DD + t];
    }
    const size_t id = (size_t)k * DD + t;
    float nw = ema_w[id] * P_DECAY + acc * (1.0f - P_DECAY);
    out_ema_w[id] = nw;
    const float n = *n_ws;
    float cl = out_cluster[k];
    float csz = (cl + P_EPS) / (n + (float)KC * P_EPS) * n;
    out_codebook[id] = nw / csz;
}

// ---------------------------------------------------------------------------
extern "C" void kernel_launch(void* const* d_in, const int* in_sizes, int n_in,
                              void* d_out, int out_size, void* d_ws, size_t ws_size,
                              hipStream_t stream) {
    const float* z      = (const float*)d_in[0];
    const float* cb     = (const float*)d_in[1];
    const float* ema_cs = (const float*)d_in[2];
    const float* ema_w  = (const float*)d_in[3];

    // workspace layout (16B-aligned first, then 4B scalars)
    float4* cand = (float4*)d_ws;                               // 2*BB float4
    int4* wl = (int4*)(cand + 2 * (size_t)BB);                  // BB int4
    unsigned short* zb = (unsigned short*)(wl + BB);            // BB*DD bf16
    unsigned short* cbb = zb + (size_t)BB * DD;                 // KC*DD bf16
    float* c_norm = (float*)(cbb + (size_t)KC * DD);            // KC
    int* idx_i = (int*)(c_norm + KC);                           // BB
    int* cnt = idx_i + BB;                                      // KC
    int* wl_cnt = cnt + KC;                                     // 1
    int* bin_start = wl_cnt + 1;                                // KC+1
    int* cursor = bin_start + KC + 1;                           // KC
    int* row_of = cursor + KC;                                  // BB
    float* commit_parts = (float*)(row_of + BB);                // BB/4
    float* n_ws = commit_parts + BB / 4;                        // 1

    float* out        = (float*)d_out;
    float* o_zq       = out;
    float* o_idx      = o_zq + (size_t)BB * DD;
    float* o_commit   = o_idx + BB;
    float* o_codebook = o_commit + 1;
    float* o_cluster  = o_codebook + (size_t)KC * DD;
    float* o_emaw     = o_cluster + KC;

    hipMemsetAsync(cnt, 0, (KC + 1) * sizeof(int), stream);  // cnt + wl_cnt

    convert_z_kernel<<<(BB * DD / 4) / 256, 256, 0, stream>>>(z, zb);
    convert_cb_kernel<<<KC / 4, 256, 0, stream>>>(cb, cbb, c_norm);
    mfma_argmin_kernel<<<(BB / 128) * 2, 256, 0, stream>>>(zb, cbb, c_norm, cand);
    merge_kernel<<<BB / 256, 256, 0, stream>>>(cand, idx_i, o_idx, wl, wl_cnt);
    refine_kernel<<<256, 256, 0, stream>>>(wl, wl_cnt, z, cb, c_norm, idx_i, o_idx);
    hist_kernel<<<BB / 256, 256, 0, stream>>>(idx_i, cnt);
    prefix_kernel<<<1, 256, 0, stream>>>(cnt, bin_start, cursor);
    scatter_ids_kernel<<<BB / 256, 256, 0, stream>>>(idx_i, cursor, row_of);
    zq_commit_kernel<<<BB / 4, 256, 0, stream>>>(z, cb, idx_i, o_zq, commit_parts);
    cluster_commit_kernel<<<1, 256, 0, stream>>>(ema_cs, cnt, commit_parts,
                                                 o_cluster, n_ws, o_commit);
    bucketsum_finalize_kernel<<<KC, 256, 0, stream>>>(z, row_of, bin_start, ema_w,
                                                      o_cluster, n_ws, o_emaw,
                                                      o_codebook);
    (void)in_sizes; (void)n_in; (void)out_size; (void)ws_size;
}

// Round 6
// 270.217 us; speedup vs baseline: 1.7355x; 1.7355x over previous
//
#include <hip/hip_runtime.h>

#define KC 4096
#define DD 256
#define BB 32768
#define P_BETA 0.25f
#define P_DECAY 0.99f
#define P_EPS 1e-5f
#define TAU 0.5f
#define CHUNK 32

typedef __attribute__((ext_vector_type(8))) short bf16x8;
typedef __attribute__((ext_vector_type(4))) float f32x4;

static __device__ __forceinline__ unsigned short f2bf(float f) {
    unsigned int u = __float_as_uint(f);
    unsigned int r = (u + 0x7fffu + ((u >> 16) & 1u)) >> 16;
    return (unsigned short)r;
}
static __device__ __forceinline__ void gload_lds16(const void* g, void* s) {
    __builtin_amdgcn_global_load_lds(
        (const __attribute__((address_space(1))) unsigned int*)g,
        (__attribute__((address_space(3))) unsigned int*)s, 16, 0, 0);
}

// ---------------------------------------------------------------------------
// convert z -> bf16
// ---------------------------------------------------------------------------
__global__ __launch_bounds__(256) void convert_z_kernel(const float* __restrict__ src,
                                                        unsigned short* __restrict__ dst) {
    int t = blockIdx.x * 256 + threadIdx.x;
    float4 v = ((const float4*)src)[t];
    *(ushort4*)&dst[(size_t)t * 4] =
        make_ushort4(f2bf(v.x), f2bf(v.y), f2bf(v.z), f2bf(v.w));
}

// ---------------------------------------------------------------------------
// convert cb -> bf16, fused exact-f32 c_norm
// ---------------------------------------------------------------------------
__global__ __launch_bounds__(256) void convert_cb_kernel(const float* __restrict__ cb,
                                                         unsigned short* __restrict__ dst,
                                                         float* __restrict__ cn) {
    int t = blockIdx.x * 256 + threadIdx.x;
    int lane = threadIdx.x & 63;
    int row = blockIdx.x * 4 + (threadIdx.x >> 6);
    float4 v = ((const float4*)cb)[t];
    *(ushort4*)&dst[(size_t)t * 4] =
        make_ushort4(f2bf(v.x), f2bf(v.y), f2bf(v.z), f2bf(v.w));
    float s = v.x * v.x + v.y * v.y + v.z * v.z + v.w * v.w;
#pragma unroll
    for (int m = 32; m; m >>= 1) s += __shfl_xor(s, m);
    if (lane == 0) cn[row] = s;
}

// ---------------------------------------------------------------------------
// MFMA argmin screening (plain bf16), persistent A-tile, XOR swizzle.
// Emits per-row top-2 per K-half.
// ---------------------------------------------------------------------------
__global__ __launch_bounds__(256, 2) void
mfma_argmin_kernel(const unsigned short* __restrict__ zb,
                   const unsigned short* __restrict__ cbb,
                   const float* __restrict__ cn,
                   float4* __restrict__ cand) {
    __shared__ unsigned short As[128 * 256];  // 64 KB persistent z-tile
    __shared__ unsigned short Bs[128 * 64];   // 16 KB per-step cb-tile

    const int tid = threadIdx.x;
    const int l = tid & 63, w = tid >> 6;
    const int xcd = blockIdx.x & 7;
    const int half = xcd >> 2;
    const int rb = (blockIdx.x >> 3) * 4 + (xcd & 3);
    const int row0 = rb * 128;
    const int col0 = half * 2048;
    const int wm = w & 1, wn = w >> 1;
    const int m_off = wm * 64, n_off = wn * 64;
    const int lm = l & 15, lq = l >> 4;

    {
        const int lrow = w * 2 + (l >> 5);
        const int coff = ((l & 31) ^ lrow) * 8;
#pragma unroll
        for (int i = 0; i < 16; ++i) {
            gload_lds16(zb + (size_t)(row0 + i * 8 + lrow) * DD + coff,
                        &As[(i * 8 + w * 2) * 256]);
        }
    }

    const int srow = l >> 3;
    const int scol = ((l & 7) ^ srow) * 8;
    const int g0 = w * 4;

    float best[16];
    int bidx[16];
#pragma unroll
    for (int s = 0; s < 16; ++s) { best[s] = 3.4e38f; bidx[s] = 0; }

    for (int kc = 0; kc < 2048; kc += 128) {
        f32x4 acc[4][4];
#pragma unroll
        for (int a = 0; a < 4; ++a)
#pragma unroll
            for (int b = 0; b < 4; ++b) acc[a][b] = (f32x4){0.f, 0.f, 0.f, 0.f};

        for (int dc = 0; dc < 4; ++dc) {
#pragma unroll
            for (int j = 0; j < 4; ++j) {
                const int g = g0 + j;
                const int br = col0 + kc + g * 8 + srow;
                gload_lds16(cbb + (size_t)br * DD + dc * 64 + scol, &Bs[g * 512]);
            }
            __syncthreads();
#pragma unroll
            for (int ks = 0; ks < 2; ++ks) {
                bf16x8 af[4], bfr[4];
                const int cbi = dc * 8 + ks * 4 + lq;
#pragma unroll
                for (int tm = 0; tm < 4; ++tm) {
                    int r = m_off + tm * 16 + lm;
                    af[tm] = *(const bf16x8*)&As[r * 256 + ((cbi ^ (r & 7)) * 8)];
                }
#pragma unroll
                for (int tn = 0; tn < 4; ++tn) {
                    int r = n_off + tn * 16 + lm;
                    bfr[tn] = *(const bf16x8*)&Bs[r * 64 + (((ks * 4 + lq) ^ (r & 7)) * 8)];
                }
#pragma unroll
                for (int tm = 0; tm < 4; ++tm)
#pragma unroll
                    for (int tn = 0; tn < 4; ++tn)
                        acc[tm][tn] = __builtin_amdgcn_mfma_f32_16x16x32_bf16(
                            af[tm], bfr[tn], acc[tm][tn], 0, 0, 0);
            }
            __syncthreads();
        }
#pragma unroll
        for (int tn = 0; tn < 4; ++tn) {
            const int col = col0 + kc + n_off + tn * 16 + lm;
            const float cnv = cn[col];
#pragma unroll
            for (int tm = 0; tm < 4; ++tm)
#pragma unroll
                for (int r = 0; r < 4; ++r) {
                    float dist = fmaf(-2.0f, acc[tm][tn][r], cnv);
                    int s = tm * 4 + r;
                    if (dist < best[s]) { best[s] = dist; bidx[s] = col; }
                }
        }
    }

    float v2[16];
    int i2[16];
#pragma unroll
    for (int s = 0; s < 16; ++s) { v2[s] = 3.4e38f; i2[s] = 0x7fffffff; }
#pragma unroll
    for (int m = 1; m < 16; m <<= 1) {
#pragma unroll
        for (int s = 0; s < 16; ++s) {
            float w1 = __shfl_xor(best[s], m); int j1 = __shfl_xor(bidx[s], m);
            float w2 = __shfl_xor(v2[s], m);   int j2 = __shfl_xor(i2[s], m);
            bool b = (w1 < best[s]) || (w1 == best[s] && j1 < bidx[s]);
            if (b) {
                bool c = (best[s] < w2) || (best[s] == w2 && bidx[s] < j2);
                v2[s] = c ? best[s] : w2; i2[s] = c ? bidx[s] : j2;
                best[s] = w1; bidx[s] = j1;
            } else {
                bool c = (w1 < v2[s]) || (w1 == v2[s] && j1 < i2[s]);
                v2[s] = c ? w1 : v2[s]; i2[s] = c ? j1 : i2[s];
            }
        }
    }

    float4* red = (float4*)As;
    if (lm == 0) {
#pragma unroll
        for (int tm = 0; tm < 4; ++tm)
#pragma unroll
            for (int r = 0; r < 4; ++r) {
                int s = tm * 4 + r;
                int row_local = m_off + tm * 16 + lq * 4 + r;
                red[wn * 128 + row_local] =
                    make_float4(best[s], __int_as_float(bidx[s]), v2[s], __int_as_float(i2[s]));
            }
    }
    __syncthreads();
    if (tid < 128) {
        float4 a = red[tid], b = red[128 + tid];
        float av1 = a.x, av2 = a.z; int ai1 = __float_as_int(a.y), ai2 = __float_as_int(a.w);
        float bv1 = b.x, bv2 = b.z; int bi1 = __float_as_int(b.y), bi2 = __float_as_int(b.w);
        float v1o, v2o; int i1o, i2o;
        bool bb = (bv1 < av1) || (bv1 == av1 && bi1 < ai1);
        if (bb) {
            v1o = bv1; i1o = bi1;
            bool c = (av1 < bv2) || (av1 == bv2 && ai1 < bi2);
            v2o = c ? av1 : bv2; i2o = c ? ai1 : bi2;
        } else {
            v1o = av1; i1o = ai1;
            bool c = (bv1 < av2) || (bv1 == av2 && bi1 < ai2);
            v2o = c ? bv1 : av2; i2o = c ? bi1 : ai2;
        }
        cand[(size_t)half * BB + row0 + tid] =
            make_float4(v1o, __int_as_float(i1o), v2o, __int_as_float(i2o));
    }
}

// ---------------------------------------------------------------------------
// merge halves; write provisional idx; append close calls to worklist
// ---------------------------------------------------------------------------
__global__ __launch_bounds__(256) void merge_kernel(
    const float4* __restrict__ cand, int* __restrict__ idx_i,
    float* __restrict__ idx_f, int4* __restrict__ wl, int* __restrict__ wl_cnt) {
    int i = blockIdx.x * 256 + threadIdx.x;
    float4 a = cand[i], b = cand[(size_t)BB + i];
    float av1 = a.x, av2 = a.z; int ai1 = __float_as_int(a.y), ai2 = __float_as_int(a.w);
    float bv1 = b.x, bv2 = b.z; int bi1 = __float_as_int(b.y), bi2 = __float_as_int(b.w);
    float v1o, v2o; int i1o, i2o;
    bool bb = (bv1 < av1) || (bv1 == av1 && bi1 < ai1);
    if (bb) {
        v1o = bv1; i1o = bi1;
        bool c = (av1 < bv2) || (av1 == bv2 && ai1 < bi2);
        v2o = c ? av1 : bv2; i2o = c ? ai1 : bi2;
    } else {
        v1o = av1; i1o = ai1;
        bool c = (bv1 < av2) || (bv1 == av2 && bi1 < ai2);
        v2o = c ? bv1 : av2; i2o = c ? bi1 : ai2;
    }
    idx_i[i] = i1o;
    idx_f[i] = (float)i1o;
    if (v2o - v1o < TAU) {
        int pos = atomicAdd(wl_cnt, 1);
        wl[pos] = make_int4(i, i1o, i2o, 0);
    }
}

// ---------------------------------------------------------------------------
// refine worklist rows exactly: one WAVE per row, coalesced float4 + shuffle
// ---------------------------------------------------------------------------
__global__ __launch_bounds__(256) void refine_kernel(
    const int4* __restrict__ wl, const int* __restrict__ wl_cnt,
    const float* __restrict__ z, const float* __restrict__ cb,
    const float* __restrict__ cn, int* __restrict__ idx_i,
    float* __restrict__ idx_f) {
    const int wave = (blockIdx.x * 256 + threadIdx.x) >> 6;  // 0..1023
    const int l = threadIdx.x & 63;
    const int n = *wl_cnt;
    for (int it = wave; it < n; it += 1024) {
        int4 e = wl[it];
        int i = e.x, k1 = e.y, k2 = e.z;
        float4 zv = ((const float4*)(z + (size_t)i * DD))[l];
        float4 p = ((const float4*)(cb + (size_t)k1 * DD))[l];
        float4 q = ((const float4*)(cb + (size_t)k2 * DD))[l];
        float s1 = zv.x * p.x + zv.y * p.y + zv.z * p.z + zv.w * p.w;
        float s2 = zv.x * q.x + zv.y * q.y + zv.z * q.z + zv.w * q.w;
#pragma unroll
        for (int m = 32; m; m >>= 1) { s1 += __shfl_xor(s1, m); s2 += __shfl_xor(s2, m); }
        float d1 = cn[k1] - 2.f * s1;
        float d2 = cn[k2] - 2.f * s2;
        int kb = (d2 < d1 || (d2 == d1 && k2 < k1)) ? k2 : k1;
        if (l == 0) { idx_i[i] = kb; idx_f[i] = (float)kb; }
    }
}

// ---------------------------------------------------------------------------
// histogram of final idx (int counts)
// ---------------------------------------------------------------------------
__global__ __launch_bounds__(256) void hist_kernel(const int* __restrict__ idx_i,
                                                   int* __restrict__ cnt) {
    int i = blockIdx.x * 256 + threadIdx.x;
    atomicAdd(&cnt[idx_i[i]], 1);
}

// ---------------------------------------------------------------------------
// exclusive prefix over 4096 bins (1 block) -> cursors
// ---------------------------------------------------------------------------
__global__ __launch_bounds__(256) void prefix_kernel(const int* __restrict__ cnt,
                                                     int* __restrict__ cursor) {
    __shared__ int ls[257];
    const int t = threadIdx.x;
    int local[16];
    int s = 0;
#pragma unroll
    for (int j = 0; j < 16; ++j) { local[j] = s; s += cnt[t * 16 + j]; }
    ls[t + 1] = s;
    __syncthreads();
    if (t == 0) {
        ls[0] = 0;
        for (int j = 1; j <= 256; ++j) ls[j] += ls[j - 1];
    }
    __syncthreads();
    int off = ls[t];
#pragma unroll
    for (int j = 0; j < 16; ++j) cursor[t * 16 + j] = off + local[j];
}

// ---------------------------------------------------------------------------
// scatter row ids into buckets, packed with code: row | (k<<16)
// ---------------------------------------------------------------------------
__global__ __launch_bounds__(256) void scatter_ids_kernel(const int* __restrict__ idx_i,
                                                          int* __restrict__ cursor,
                                                          int* __restrict__ row_of) {
    int i = blockIdx.x * 256 + threadIdx.x;
    int k = idx_i[i];
    int pos = atomicAdd(&cursor[k], 1);
    row_of[pos] = i | (k << 16);
}

// ---------------------------------------------------------------------------
// balanced bucket sum: block b handles CHUNK consecutive positions of the
// code-sorted row list; thread t owns dim t; flush partial at code-run ends.
// Uniform branch (same code sequence across all threads of the block).
// ---------------------------------------------------------------------------
__global__ __launch_bounds__(256) void bucket_chunk_kernel(
    const float* __restrict__ z, const int* __restrict__ row_of,
    float* __restrict__ dw) {
    __shared__ int pk[CHUNK];
    const int t = threadIdx.x;
    const int p0 = blockIdx.x * CHUNK;
    if (t < CHUNK) pk[t] = row_of[p0 + t];
    __syncthreads();
    float acc = 0.f;
    int kprev = pk[0] >> 16;
#pragma unroll 4
    for (int j = 0; j < CHUNK; ++j) {
        int p = pk[j];
        int r = p & 0xffff, k = p >> 16;
        if (k != kprev) {
            atomicAdd(&dw[(size_t)kprev * DD + t], acc);
            acc = 0.f;
            kprev = k;
        }
        acc += z[(size_t)r * DD + t];
    }
    atomicAdd(&dw[(size_t)kprev * DD + t], acc);
}

// ---------------------------------------------------------------------------
// z_q gather + commit partials (no atomics): 4 rows per block
// ---------------------------------------------------------------------------
__global__ __launch_bounds__(256) void zq_commit_kernel(const float* __restrict__ z,
                                                        const float* __restrict__ cb,
                                                        const int* __restrict__ idx_i,
                                                        float* __restrict__ zq,
                                                        float* __restrict__ commit_parts) {
    const int w = threadIdx.x >> 6, l = threadIdx.x & 63;
    const int i = blockIdx.x * 4 + w;
    const int k = idx_i[i];
    float4 zv = ((const float4*)z)[(size_t)i * 64 + l];
    float4 cv = ((const float4*)cb)[(size_t)k * 64 + l];
    ((float4*)zq)[(size_t)i * 64 + l] = cv;
    float dx = zv.x - cv.x, dy = zv.y - cv.y, dz = zv.z - cv.z, dq = zv.w - cv.w;
    float s = dx * dx + dy * dy + dz * dz + dq * dq;
#pragma unroll
    for (int m = 32; m; m >>= 1) s += __shfl_xor(s, m);
    __shared__ float ls[4];
    if (l == 0) ls[w] = s;
    __syncthreads();
    if (threadIdx.x == 0) commit_parts[blockIdx.x] = ls[0] + ls[1] + ls[2] + ls[3];
}

// ---------------------------------------------------------------------------
// single block: commit reduce + new_cluster + n
// ---------------------------------------------------------------------------
__global__ __launch_bounds__(256) void cluster_commit_kernel(
    const float* __restrict__ ema_cs, const int* __restrict__ cnt,
    const float* __restrict__ commit_parts, float* __restrict__ out_cluster,
    float* __restrict__ n_ws, float* __restrict__ out_commit) {
    const int t = threadIdx.x;
    float cs = 0.f;
    for (int j = t; j < BB / 4; j += 256) cs += commit_parts[j];
    float ns = 0.f;
    for (int j = t; j < KC; j += 256) {
        float nc = ema_cs[j] * P_DECAY + (float)cnt[j] * (1.0f - P_DECAY);
        out_cluster[j] = nc;
        ns += nc;
    }
#pragma unroll
    for (int m = 32; m; m >>= 1) { cs += __shfl_xor(cs, m); ns += __shfl_xor(ns, m); }
    __shared__ float lc[4], ln[4];
    if ((t & 63) == 0) { lc[t >> 6] = cs; ln[t >> 6] = ns; }
    __syncthreads();
    if (t == 0) {
        *out_commit = P_BETA * (lc[0] + lc[1] + lc[2] + lc[3]) / (float)((size_t)BB * DD);
        *n_ws = ln[0] + ln[1] + ln[2] + ln[3];
    }
}

// ---------------------------------------------------------------------------
// finalize new_ema_weight & new_codebook from dw
// ---------------------------------------------------------------------------
__global__ __launch_bounds__(256) void finalize_kernel(const float* __restrict__ ema_w,
                                                       const float* __restrict__ dw,
                                                       const float* __restrict__ out_cluster,
                                                       const float* __restrict__ n_ws,
                                                       float* __restrict__ out_ema_w,
                                                       float* __restrict__ out_codebook) {
    const size_t id = (size_t)blockIdx.x * 256 + threadIdx.x;
    const int k = (int)(id >> 8);
    const float n = *n_ws;
    float nw = ema_w[id] * P_DECAY + dw[id] * (1.0f - P_DECAY);
    out_ema_w[id] = nw;
    float cl = out_cluster[k];
    float csz = (cl + P_EPS) / (n + (float)KC * P_EPS) * n;
    out_codebook[id] = nw / csz;
}

// ---------------------------------------------------------------------------
extern "C" void kernel_launch(void* const* d_in, const int* in_sizes, int n_in,
                              void* d_out, int out_size, void* d_ws, size_t ws_size,
                              hipStream_t stream) {
    const float* z      = (const float*)d_in[0];
    const float* cb     = (const float*)d_in[1];
    const float* ema_cs = (const float*)d_in[2];
    const float* ema_w  = (const float*)d_in[3];

    // workspace layout (16B-aligned first, then 4B scalars)
    float4* cand = (float4*)d_ws;                               // 2*BB float4
    int4* wl = (int4*)(cand + 2 * (size_t)BB);                  // BB int4
    unsigned short* zb = (unsigned short*)(wl + BB);            // BB*DD bf16
    unsigned short* cbb = zb + (size_t)BB * DD;                 // KC*DD bf16
    float* dw = (float*)(cbb + (size_t)KC * DD);                // KC*DD f32
    float* c_norm = dw + (size_t)KC * DD;                       // KC
    int* idx_i = (int*)(c_norm + KC);                           // BB
    int* cnt = idx_i + BB;                                      // KC
    int* wl_cnt = cnt + KC;                                     // 1
    int* cursor = wl_cnt + 1;                                   // KC
    int* row_of = cursor + KC;                                  // BB
    float* commit_parts = (float*)(row_of + BB);                // BB/4
    float* n_ws = commit_parts + BB / 4;                        // 1

    float* out        = (float*)d_out;
    float* o_zq       = out;
    float* o_idx      = o_zq + (size_t)BB * DD;
    float* o_commit   = o_idx + BB;
    float* o_codebook = o_commit + 1;
    float* o_cluster  = o_codebook + (size_t)KC * DD;
    float* o_emaw     = o_cluster + KC;

    hipMemsetAsync(cnt, 0, (KC + 1) * sizeof(int), stream);      // cnt + wl_cnt
    hipMemsetAsync(dw, 0, (size_t)KC * DD * sizeof(float), stream);

    convert_z_kernel<<<(BB * DD / 4) / 256, 256, 0, stream>>>(z, zb);
    convert_cb_kernel<<<KC / 4, 256, 0, stream>>>(cb, cbb, c_norm);
    mfma_argmin_kernel<<<(BB / 128) * 2, 256, 0, stream>>>(zb, cbb, c_norm, cand);
    merge_kernel<<<BB / 256, 256, 0, stream>>>(cand, idx_i, o_idx, wl, wl_cnt);
    refine_kernel<<<256, 256, 0, stream>>>(wl, wl_cnt, z, cb, c_norm, idx_i, o_idx);
    hist_kernel<<<BB / 256, 256, 0, stream>>>(idx_i, cnt);
    prefix_kernel<<<1, 256, 0, stream>>>(cnt, cursor);
    scatter_ids_kernel<<<BB / 256, 256, 0, stream>>>(idx_i, cursor, row_of);
    bucket_chunk_kernel<<<BB / CHUNK, 256, 0, stream>>>(z, row_of, dw);
    zq_commit_kernel<<<BB / 4, 256, 0, stream>>>(z, cb, idx_i, o_zq, commit_parts);
    cluster_commit_kernel<<<1, 256, 0, stream>>>(ema_cs, cnt, commit_parts,
                                                 o_cluster, n_ws, o_commit);
    finalize_kernel<<<(KC * DD) / 256, 256, 0, stream>>>(ema_w, dw, o_cluster, n_ws,
                                                         o_emaw, o_codebook);
    (void)in_sizes; (void)n_in; (void)out_size; (void)ws_size;
}

// Round 7
// 237.930 us; speedup vs baseline: 1.9710x; 1.1357x over previous
//
#include <hip/hip_runtime.h>

#define KC 4096
#define DD 256
#define BB 32768
#define P_BETA 0.25f
#define P_DECAY 0.99f
#define P_EPS 1e-5f
#define TAU 0.5f
#define CHUNK 32

typedef __attribute__((ext_vector_type(8))) short bf16x8;
typedef __attribute__((ext_vector_type(4))) float f32x4;

static __device__ __forceinline__ unsigned short f2bf(float f) {
    unsigned int u = __float_as_uint(f);
    unsigned int r = (u + 0x7fffu + ((u >> 16) & 1u)) >> 16;
    return (unsigned short)r;
}
static __device__ __forceinline__ void gload_lds16(const void* g, void* s) {
    __builtin_amdgcn_global_load_lds(
        (const __attribute__((address_space(1))) unsigned int*)g,
        (__attribute__((address_space(3))) unsigned int*)s, 16, 0, 0);
}

// ---------------------------------------------------------------------------
// Fused prep: blocks [0,8192) convert z; [8192,9216) convert cb + c_norm;
// block 9216 zeros cnt.   Replaces 2 kernels + 1 memset.
// ---------------------------------------------------------------------------
#define ZBLK (BB * DD / 4 / 256)   // 8192
#define CBLK (KC * DD / 4 / 256)   // 1024
__global__ __launch_bounds__(256) void convert_all_kernel(
    const float* __restrict__ z, const float* __restrict__ cb,
    unsigned short* __restrict__ zb, unsigned short* __restrict__ cbb,
    float* __restrict__ cn, int* __restrict__ cnt) {
    const int b = blockIdx.x;
    if (b < ZBLK) {
        int t = b * 256 + threadIdx.x;
        float4 v = ((const float4*)z)[t];
        *(ushort4*)&zb[(size_t)t * 4] =
            make_ushort4(f2bf(v.x), f2bf(v.y), f2bf(v.z), f2bf(v.w));
    } else if (b < ZBLK + CBLK) {
        int t = (b - ZBLK) * 256 + threadIdx.x;
        int lane = threadIdx.x & 63;
        int row = (b - ZBLK) * 4 + (threadIdx.x >> 6);
        float4 v = ((const float4*)cb)[t];
        *(ushort4*)&cbb[(size_t)t * 4] =
            make_ushort4(f2bf(v.x), f2bf(v.y), f2bf(v.z), f2bf(v.w));
        float s = v.x * v.x + v.y * v.y + v.z * v.z + v.w * v.w;
#pragma unroll
        for (int m = 32; m; m >>= 1) s += __shfl_xor(s, m);
        if (lane == 0) cn[row] = s;
    } else {
        // zero cnt: 4096 ints = 1024 int4, 4 per thread
        int4* p = (int4*)cnt;
        int4 zv = make_int4(0, 0, 0, 0);
#pragma unroll
        for (int j = 0; j < 4; ++j) p[threadIdx.x * 4 + j] = zv;
    }
}

// ---------------------------------------------------------------------------
// MFMA argmin screening (plain bf16), persistent A-tile, XOR swizzle.
// Emits per-row top-2 per K-half.  (unchanged from R6)
// ---------------------------------------------------------------------------
__global__ __launch_bounds__(256, 2) void
mfma_argmin_kernel(const unsigned short* __restrict__ zb,
                   const unsigned short* __restrict__ cbb,
                   const float* __restrict__ cn,
                   float4* __restrict__ cand) {
    __shared__ unsigned short As[128 * 256];  // 64 KB persistent z-tile
    __shared__ unsigned short Bs[128 * 64];   // 16 KB per-step cb-tile

    const int tid = threadIdx.x;
    const int l = tid & 63, w = tid >> 6;
    const int xcd = blockIdx.x & 7;
    const int half = xcd >> 2;
    const int rb = (blockIdx.x >> 3) * 4 + (xcd & 3);
    const int row0 = rb * 128;
    const int col0 = half * 2048;
    const int wm = w & 1, wn = w >> 1;
    const int m_off = wm * 64, n_off = wn * 64;
    const int lm = l & 15, lq = l >> 4;

    {
        const int lrow = w * 2 + (l >> 5);
        const int coff = ((l & 31) ^ lrow) * 8;
#pragma unroll
        for (int i = 0; i < 16; ++i) {
            gload_lds16(zb + (size_t)(row0 + i * 8 + lrow) * DD + coff,
                        &As[(i * 8 + w * 2) * 256]);
        }
    }

    const int srow = l >> 3;
    const int scol = ((l & 7) ^ srow) * 8;
    const int g0 = w * 4;

    float best[16];
    int bidx[16];
#pragma unroll
    for (int s = 0; s < 16; ++s) { best[s] = 3.4e38f; bidx[s] = 0; }

    for (int kc = 0; kc < 2048; kc += 128) {
        f32x4 acc[4][4];
#pragma unroll
        for (int a = 0; a < 4; ++a)
#pragma unroll
            for (int b = 0; b < 4; ++b) acc[a][b] = (f32x4){0.f, 0.f, 0.f, 0.f};

        for (int dc = 0; dc < 4; ++dc) {
#pragma unroll
            for (int j = 0; j < 4; ++j) {
                const int g = g0 + j;
                const int br = col0 + kc + g * 8 + srow;
                gload_lds16(cbb + (size_t)br * DD + dc * 64 + scol, &Bs[g * 512]);
            }
            __syncthreads();
#pragma unroll
            for (int ks = 0; ks < 2; ++ks) {
                bf16x8 af[4], bfr[4];
                const int cbi = dc * 8 + ks * 4 + lq;
#pragma unroll
                for (int tm = 0; tm < 4; ++tm) {
                    int r = m_off + tm * 16 + lm;
                    af[tm] = *(const bf16x8*)&As[r * 256 + ((cbi ^ (r & 7)) * 8)];
                }
#pragma unroll
                for (int tn = 0; tn < 4; ++tn) {
                    int r = n_off + tn * 16 + lm;
                    bfr[tn] = *(const bf16x8*)&Bs[r * 64 + (((ks * 4 + lq) ^ (r & 7)) * 8)];
                }
#pragma unroll
                for (int tm = 0; tm < 4; ++tm)
#pragma unroll
                    for (int tn = 0; tn < 4; ++tn)
                        acc[tm][tn] = __builtin_amdgcn_mfma_f32_16x16x32_bf16(
                            af[tm], bfr[tn], acc[tm][tn], 0, 0, 0);
            }
            __syncthreads();
        }
#pragma unroll
        for (int tn = 0; tn < 4; ++tn) {
            const int col = col0 + kc + n_off + tn * 16 + lm;
            const float cnv = cn[col];
#pragma unroll
            for (int tm = 0; tm < 4; ++tm)
#pragma unroll
                for (int r = 0; r < 4; ++r) {
                    float dist = fmaf(-2.0f, acc[tm][tn][r], cnv);
                    int s = tm * 4 + r;
                    if (dist < best[s]) { best[s] = dist; bidx[s] = col; }
                }
        }
    }

    float v2[16];
    int i2[16];
#pragma unroll
    for (int s = 0; s < 16; ++s) { v2[s] = 3.4e38f; i2[s] = 0x7fffffff; }
#pragma unroll
    for (int m = 1; m < 16; m <<= 1) {
#pragma unroll
        for (int s = 0; s < 16; ++s) {
            float w1 = __shfl_xor(best[s], m); int j1 = __shfl_xor(bidx[s], m);
            float w2 = __shfl_xor(v2[s], m);   int j2 = __shfl_xor(i2[s], m);
            bool b = (w1 < best[s]) || (w1 == best[s] && j1 < bidx[s]);
            if (b) {
                bool c = (best[s] < w2) || (best[s] == w2 && bidx[s] < j2);
                v2[s] = c ? best[s] : w2; i2[s] = c ? bidx[s] : j2;
                best[s] = w1; bidx[s] = j1;
            } else {
                bool c = (w1 < v2[s]) || (w1 == v2[s] && j1 < i2[s]);
                v2[s] = c ? w1 : v2[s]; i2[s] = c ? j1 : i2[s];
            }
        }
    }

    float4* red = (float4*)As;
    if (lm == 0) {
#pragma unroll
        for (int tm = 0; tm < 4; ++tm)
#pragma unroll
            for (int r = 0; r < 4; ++r) {
                int s = tm * 4 + r;
                int row_local = m_off + tm * 16 + lq * 4 + r;
                red[wn * 128 + row_local] =
                    make_float4(best[s], __int_as_float(bidx[s]), v2[s], __int_as_float(i2[s]));
            }
    }
    __syncthreads();
    if (tid < 128) {
        float4 a = red[tid], b = red[128 + tid];
        float av1 = a.x, av2 = a.z; int ai1 = __float_as_int(a.y), ai2 = __float_as_int(a.w);
        float bv1 = b.x, bv2 = b.z; int bi1 = __float_as_int(b.y), bi2 = __float_as_int(b.w);
        float v1o, v2o; int i1o, i2o;
        bool bb = (bv1 < av1) || (bv1 == av1 && bi1 < ai1);
        if (bb) {
            v1o = bv1; i1o = bi1;
            bool c = (av1 < bv2) || (av1 == bv2 && ai1 < bi2);
            v2o = c ? av1 : bv2; i2o = c ? ai1 : bi2;
        } else {
            v1o = av1; i1o = ai1;
            bool c = (bv1 < av2) || (bv1 == av2 && bi1 < ai2);
            v2o = c ? bv1 : av2; i2o = c ? bi1 : ai2;
        }
        cand[(size_t)half * BB + row0 + tid] =
            make_float4(v1o, __int_as_float(i1o), v2o, __int_as_float(i2o));
    }
}

// ---------------------------------------------------------------------------
// Fused: merge halves + exact f32 re-check (per-thread, gap<TAU) + hist
// + dw zeroing.   Replaces 3 kernels + 1 memset.  Grid = BB/256 = 128.
// ---------------------------------------------------------------------------
__global__ __launch_bounds__(256) void merge_refine_kernel(
    const float4* __restrict__ cand, const float* __restrict__ z,
    const float* __restrict__ cb, const float* __restrict__ cn,
    int* __restrict__ idx_i, float* __restrict__ idx_f,
    int* __restrict__ cnt, float* __restrict__ dw) {
    int i = blockIdx.x * 256 + threadIdx.x;
    // zero dw: 128*256 threads x 8 float4 = 1M floats = KC*DD
    {
        float4 zv4 = make_float4(0.f, 0.f, 0.f, 0.f);
        float4* dp = (float4*)dw;
        int base = i * 8;
#pragma unroll
        for (int j = 0; j < 8; ++j) dp[base + j] = zv4;
    }
    float4 a = cand[i], b = cand[(size_t)BB + i];
    float av1 = a.x, av2 = a.z; int ai1 = __float_as_int(a.y), ai2 = __float_as_int(a.w);
    float bv1 = b.x, bv2 = b.z; int bi1 = __float_as_int(b.y), bi2 = __float_as_int(b.w);
    float v1o, v2o; int i1o, i2o;
    bool bb = (bv1 < av1) || (bv1 == av1 && bi1 < ai1);
    if (bb) {
        v1o = bv1; i1o = bi1;
        bool c = (av1 < bv2) || (av1 == bv2 && ai1 < bi2);
        v2o = c ? av1 : bv2; i2o = c ? ai1 : bi2;
    } else {
        v1o = av1; i1o = ai1;
        bool c = (bv1 < av2) || (bv1 == av2 && bi1 < ai2);
        v2o = c ? bv1 : av2; i2o = c ? bi1 : ai2;
    }
    int kb = i1o;
    if (v2o - v1o < TAU) {
        const float4* zr = (const float4*)(z + (size_t)i * DD);
        const float4* c1 = (const float4*)(cb + (size_t)i1o * DD);
        const float4* c2 = (const float4*)(cb + (size_t)i2o * DD);
        float s1x = 0, s1y = 0, s1z = 0, s1w = 0;
        float s2x = 0, s2y = 0, s2z = 0, s2w = 0;
        for (int j = 0; j < 64; ++j) {
            float4 zv = zr[j], p = c1[j], q = c2[j];
            s1x = fmaf(zv.x, p.x, s1x); s1y = fmaf(zv.y, p.y, s1y);
            s1z = fmaf(zv.z, p.z, s1z); s1w = fmaf(zv.w, p.w, s1w);
            s2x = fmaf(zv.x, q.x, s2x); s2y = fmaf(zv.y, q.y, s2y);
            s2z = fmaf(zv.z, q.z, s2z); s2w = fmaf(zv.w, q.w, s2w);
        }
        float d1 = cn[i1o] - 2.f * ((s1x + s1y) + (s1z + s1w));
        float d2 = cn[i2o] - 2.f * ((s2x + s2y) + (s2z + s2w));
        if (d2 < d1 || (d2 == d1 && i2o < i1o)) kb = i2o;
    }
    idx_i[i] = kb;
    idx_f[i] = (float)kb;
    atomicAdd(&cnt[kb], 1);
}

// ---------------------------------------------------------------------------
// exclusive prefix over 4096 bins (1 block) -> cursors
// ---------------------------------------------------------------------------
__global__ __launch_bounds__(256) void prefix_kernel(const int* __restrict__ cnt,
                                                     int* __restrict__ cursor) {
    __shared__ int ls[257];
    const int t = threadIdx.x;
    int local[16];
    int s = 0;
#pragma unroll
    for (int j = 0; j < 16; ++j) { local[j] = s; s += cnt[t * 16 + j]; }
    ls[t + 1] = s;
    __syncthreads();
    if (t == 0) {
        ls[0] = 0;
        for (int j = 1; j <= 256; ++j) ls[j] += ls[j - 1];
    }
    __syncthreads();
    int off = ls[t];
#pragma unroll
    for (int j = 0; j < 16; ++j) cursor[t * 16 + j] = off + local[j];
}

// ---------------------------------------------------------------------------
// Fused: z_q gather + commit partials + bucket id scatter.  4 rows/block.
// ---------------------------------------------------------------------------
__global__ __launch_bounds__(256) void zq_commit_scatter_kernel(
    const float* __restrict__ z, const float* __restrict__ cb,
    const int* __restrict__ idx_i, float* __restrict__ zq,
    float* __restrict__ commit_parts, int* __restrict__ cursor,
    int* __restrict__ row_of) {
    const int w = threadIdx.x >> 6, l = threadIdx.x & 63;
    const int i = blockIdx.x * 4 + w;
    const int k = idx_i[i];
    float4 zv = ((const float4*)z)[(size_t)i * 64 + l];
    float4 cv = ((const float4*)cb)[(size_t)k * 64 + l];
    ((float4*)zq)[(size_t)i * 64 + l] = cv;
    float dx = zv.x - cv.x, dy = zv.y - cv.y, dz = zv.z - cv.z, dq = zv.w - cv.w;
    float s = dx * dx + dy * dy + dz * dz + dq * dq;
#pragma unroll
    for (int m = 32; m; m >>= 1) s += __shfl_xor(s, m);
    __shared__ float ls[4];
    if (l == 0) {
        ls[w] = s;
        int pos = atomicAdd(&cursor[k], 1);
        row_of[pos] = i | (k << 16);
    }
    __syncthreads();
    if (threadIdx.x == 0) commit_parts[blockIdx.x] = ls[0] + ls[1] + ls[2] + ls[3];
}

// ---------------------------------------------------------------------------
// Fused: balanced bucket sum (blocks 0..BB/CHUNK-1) + cluster/commit reduce
// (block BB/CHUNK).   Replaces 2 kernels.
// ---------------------------------------------------------------------------
__global__ __launch_bounds__(256) void bucket_cluster_kernel(
    const float* __restrict__ z, const int* __restrict__ row_of,
    float* __restrict__ dw, const float* __restrict__ ema_cs,
    const int* __restrict__ cnt, const float* __restrict__ commit_parts,
    float* __restrict__ out_cluster, float* __restrict__ n_ws,
    float* __restrict__ out_commit) {
    const int t = threadIdx.x;
    if (blockIdx.x == BB / CHUNK) {
        float cs = 0.f;
        for (int j = t; j < BB / 4; j += 256) cs += commit_parts[j];
        float ns = 0.f;
        for (int j = t; j < KC; j += 256) {
            float nc = ema_cs[j] * P_DECAY + (float)cnt[j] * (1.0f - P_DECAY);
            out_cluster[j] = nc;
            ns += nc;
        }
#pragma unroll
        for (int m = 32; m; m >>= 1) { cs += __shfl_xor(cs, m); ns += __shfl_xor(ns, m); }
        __shared__ float lc[4], ln[4];
        if ((t & 63) == 0) { lc[t >> 6] = cs; ln[t >> 6] = ns; }
        __syncthreads();
        if (t == 0) {
            *out_commit = P_BETA * (lc[0] + lc[1] + lc[2] + lc[3]) / (float)((size_t)BB * DD);
            *n_ws = ln[0] + ln[1] + ln[2] + ln[3];
        }
        return;
    }
    __shared__ int pk[CHUNK];
    const int p0 = blockIdx.x * CHUNK;
    if (t < CHUNK) pk[t] = row_of[p0 + t];
    __syncthreads();
    float acc = 0.f;
    int kprev = pk[0] >> 16;
#pragma unroll 4
    for (int j = 0; j < CHUNK; ++j) {
        int p = pk[j];
        int r = p & 0xffff, k = p >> 16;
        if (k != kprev) {
            atomicAdd(&dw[(size_t)kprev * DD + t], acc);
            acc = 0.f;
            kprev = k;
        }
        acc += z[(size_t)r * DD + t];
    }
    atomicAdd(&dw[(size_t)kprev * DD + t], acc);
}

// ---------------------------------------------------------------------------
// finalize new_ema_weight & new_codebook from dw
// ---------------------------------------------------------------------------
__global__ __launch_bounds__(256) void finalize_kernel(const float* __restrict__ ema_w,
                                                       const float* __restrict__ dw,
                                                       const float* __restrict__ out_cluster,
                                                       const float* __restrict__ n_ws,
                                                       float* __restrict__ out_ema_w,
                                                       float* __restrict__ out_codebook) {
    const size_t id = (size_t)blockIdx.x * 256 + threadIdx.x;
    const int k = (int)(id >> 8);
    const float n = *n_ws;
    float nw = ema_w[id] * P_DECAY + dw[id] * (1.0f - P_DECAY);
    out_ema_w[id] = nw;
    float cl = out_cluster[k];
    float csz = (cl + P_EPS) / (n + (float)KC * P_EPS) * n;
    out_codebook[id] = nw / csz;
}

// ---------------------------------------------------------------------------
extern "C" void kernel_launch(void* const* d_in, const int* in_sizes, int n_in,
                              void* d_out, int out_size, void* d_ws, size_t ws_size,
                              hipStream_t stream) {
    const float* z      = (const float*)d_in[0];
    const float* cb     = (const float*)d_in[1];
    const float* ema_cs = (const float*)d_in[2];
    const float* ema_w  = (const float*)d_in[3];

    // workspace layout (16B-aligned first, then 4B scalars)
    float4* cand = (float4*)d_ws;                               // 2*BB float4
    unsigned short* zb = (unsigned short*)(cand + 2 * (size_t)BB);  // BB*DD bf16
    unsigned short* cbb = zb + (size_t)BB * DD;                 // KC*DD bf16
    float* dw = (float*)(cbb + (size_t)KC * DD);                // KC*DD f32
    float* c_norm = dw + (size_t)KC * DD;                       // KC
    int* idx_i = (int*)(c_norm + KC);                           // BB
    int* cnt = idx_i + BB;                                      // KC
    int* cursor = cnt + KC;                                     // KC
    int* row_of = cursor + KC;                                  // BB
    float* commit_parts = (float*)(row_of + BB);                // BB/4
    float* n_ws = commit_parts + BB / 4;                        // 1

    float* out        = (float*)d_out;
    float* o_zq       = out;
    float* o_idx      = o_zq + (size_t)BB * DD;
    float* o_commit   = o_idx + BB;
    float* o_codebook = o_commit + 1;
    float* o_cluster  = o_codebook + (size_t)KC * DD;
    float* o_emaw     = o_cluster + KC;

    convert_all_kernel<<<ZBLK + CBLK + 1, 256, 0, stream>>>(z, cb, zb, cbb, c_norm, cnt);
    mfma_argmin_kernel<<<(BB / 128) * 2, 256, 0, stream>>>(zb, cbb, c_norm, cand);
    merge_refine_kernel<<<BB / 256, 256, 0, stream>>>(cand, z, cb, c_norm, idx_i,
                                                      o_idx, cnt, dw);
    prefix_kernel<<<1, 256, 0, stream>>>(cnt, cursor);
    zq_commit_scatter_kernel<<<BB / 4, 256, 0, stream>>>(z, cb, idx_i, o_zq,
                                                         commit_parts, cursor, row_of);
    bucket_cluster_kernel<<<BB / CHUNK + 1, 256, 0, stream>>>(z, row_of, dw, ema_cs,
                                                              cnt, commit_parts,
                                                              o_cluster, n_ws, o_commit);
    finalize_kernel<<<(KC * DD) / 256, 256, 0, stream>>>(ema_w, dw, o_cluster, n_ws,
                                                         o_emaw, o_codebook);
    (void)in_sizes; (void)n_in; (void)out_size; (void)ws_size;
}